// Round 1
// baseline (1265.084 us; speedup 1.0000x reference)
//
#include <hip/hip_runtime.h>
#include <cmath>

// Decoder step: B=128, S=128, H=1024, E=512, V=32000
// R2 changes vs baseline (1196 us):
//  - LDS XOR swizzle (16B chunk ^ (row&7)) on As/Bs: kills 16-way ds_read_b128 conflicts
//  - W1/Whh/Wih pre-converted to bf16 into d_out (scratch until final GEMM): kills
//    in-loop f2bf for weight staging, halves Wih HBM read
//  - scores GEMM grid (8,128) N-fastest: enc-slice sharers concurrent -> ~1x enc fetch
//  - attn_combine: float4 loads, 256 blocks
// ws layout (float units) unchanged:
//   hproj f32 [128*1024]      off 0
//   scores f32 [16384]        off 131072
//   xbuf bf16 [128*2560]      off 147456
//   c1   bf16 [128*3584]      off 311296
//   gx   f32 [128*3072]       off 540672
//   gh   f32 [128*3072]       off 933888
//   total 5.31 MB
// d_out scratch (16.38 MB, overwritten by final GEMM):
//   w1bf  [1024*3072] bf16 (6.29 MB)   whhbf [3072*1024] bf16 (6.29 MB)
//   wihbf [3072*2560] bf16 (15.7 MB)   (reuses w1bf region after attention GEMMs)

#define DEVINL __device__ __forceinline__

typedef __attribute__((ext_vector_type(8))) __bf16 bf16x8;
typedef __attribute__((ext_vector_type(4))) float f32x4;
typedef __attribute__((ext_vector_type(8))) unsigned short u16x8;

DEVINL unsigned short f2bf(float f) {
    unsigned u = __builtin_bit_cast(unsigned, f);
    unsigned r = (u + 0x7FFFu + ((u >> 16) & 1u)) >> 16;
    return (unsigned short)r;
}

DEVINL float fast_tanh(float x) {
    x = fminf(15.0f, fmaxf(-15.0f, x));
    float e = __expf(2.0f * x);
    return (e - 1.0f) / (e + 1.0f);
}

DEVINL float sigmoidf_(float x) { return 1.0f / (1.0f + __expf(-x)); }

// ---------------- fp32 -> bf16 streaming convert ----------------
__global__ void cvt_bf16_k(const float* __restrict__ in,
                           unsigned short* __restrict__ out, int n8) {
    int id = blockIdx.x * blockDim.x + threadIdx.x;
    if (id >= n8) return;
    const float* p = in + (size_t)id * 8;
    float4 a = *(const float4*)p;
    float4 c = *(const float4*)(p + 4);
    u16x8 s;
    s[0] = f2bf(a.x); s[1] = f2bf(a.y); s[2] = f2bf(a.z); s[3] = f2bf(a.w);
    s[4] = f2bf(c.x); s[5] = f2bf(c.y); s[6] = f2bf(c.z); s[7] = f2bf(c.w);
    *(u16x8*)(out + (size_t)id * 8) = s;
}

// ---------------- prep ----------------
__global__ void embed_gather_k(const int* __restrict__ tl,
                               const float* __restrict__ emb,
                               unsigned short* __restrict__ xbuf,
                               unsigned short* __restrict__ c1) {
    int id = blockIdx.x * blockDim.x + threadIdx.x;
    if (id >= 128 * 512) return;
    int b = id >> 9, e = id & 511;
    unsigned short v = f2bf(emb[(size_t)tl[b] * 512 + e]);
    xbuf[b * 2560 + e] = v;
    c1[b * 3584 + 3072 + e] = v;
}

// ---------------- unified dbuf MFMA GEMM ----------------
// C[128 x N] = A[128 x K] @ W[N x K]^T (+bias). Tiles: BM=128, BN, BK=64.
// ADT: 0 = A fp32 (cvt on stage), 1 = A bf16 (copy)
// WDT: 0 = W fp32 (cvt on stage), 1 = W bf16 (copy)
// EPI: 0 = bias + fp32 store; 1 = fused tanh/W2 score reduction (grid (8,128))
// LDS tiles are row-major [rows][64] bf16 with 16B chunks XOR-swizzled by (row&7).
template<int BN, int ADT, int WDT, int EPI>
__global__ void __launch_bounds__(256)
gemm_tpl(const void* __restrict__ Av, int lda,
         const void* __restrict__ Wv, int ldw,
         const float* __restrict__ bias,
         float* __restrict__ C, int ldc, int K,
         const float* __restrict__ hproj,
         const float* __restrict__ W2v,
         float* __restrict__ scores) {
    constexpr int JF = BN / 32;      // n-frags per wave
    constexpr int ACH = 4;           // A 16B-chunks per thread (128*8/256)
    constexpr int WCH = BN / 32;     // W 16B-chunks per thread (BN*8/256)

    __shared__ unsigned short As[2][128 * 64];
    __shared__ unsigned short Bs[2][BN * 64];

    const int t = threadIdx.x;
    const int m0 = (EPI == 1) ? blockIdx.y * 128 : 0;
    const int n0 = blockIdx.x * BN;
    const int wid = t >> 6, lane = t & 63;
    const int wm = (wid & 1) * 64;
    const int wn = (wid >> 1) * (JF * 16);
    const int quad = lane >> 4, l16 = lane & 15;

    const float* Af = (const float*)Av;
    const unsigned short* Ab = (const unsigned short*)Av;
    const float* Wf = (const float*)Wv;
    const unsigned short* Wb = (const unsigned short*)Wv;

    f32x4 acc[4][JF] = {};
    float4 paf[ADT == 0 ? 2 * ACH : 1];
    uint4 pab[ADT == 1 ? ACH : 1];
    float4 pwf[WDT == 0 ? 2 * WCH : 1];
    uint4 pwb[WDT == 1 ? WCH : 1];

    auto issue = [&](int k0) {
        for (int i = 0; i < ACH; ++i) {
            int idx = t + i * 256, row = idx >> 3, c8 = (idx & 7) * 8;
            if constexpr (ADT == 0) {
                const float* p = Af + (size_t)(m0 + row) * lda + k0 + c8;
                paf[2 * i] = *(const float4*)p;
                paf[2 * i + 1] = *(const float4*)(p + 4);
            } else {
                pab[i] = *(const uint4*)(Ab + (size_t)(m0 + row) * lda + k0 + c8);
            }
        }
        for (int i = 0; i < WCH; ++i) {
            int idx = t + i * 256, row = idx >> 3, c8 = (idx & 7) * 8;
            if constexpr (WDT == 0) {
                const float* p = Wf + (size_t)(n0 + row) * ldw + k0 + c8;
                pwf[2 * i] = *(const float4*)p;
                pwf[2 * i + 1] = *(const float4*)(p + 4);
            } else {
                pwb[i] = *(const uint4*)(Wb + (size_t)(n0 + row) * ldw + k0 + c8);
            }
        }
    };
    auto commit = [&](int buf) {
        for (int i = 0; i < ACH; ++i) {
            int idx = t + i * 256, row = idx >> 3, c = idx & 7;
            unsigned short* dst = &As[buf][row * 64 + ((c ^ (row & 7)) << 3)];
            if constexpr (ADT == 0) {
                u16x8 s;
                s[0] = f2bf(paf[2 * i].x); s[1] = f2bf(paf[2 * i].y);
                s[2] = f2bf(paf[2 * i].z); s[3] = f2bf(paf[2 * i].w);
                s[4] = f2bf(paf[2 * i + 1].x); s[5] = f2bf(paf[2 * i + 1].y);
                s[6] = f2bf(paf[2 * i + 1].z); s[7] = f2bf(paf[2 * i + 1].w);
                *(u16x8*)dst = s;
            } else {
                *(uint4*)dst = pab[i];
            }
        }
        for (int i = 0; i < WCH; ++i) {
            int idx = t + i * 256, row = idx >> 3, c = idx & 7;
            unsigned short* dst = &Bs[buf][row * 64 + ((c ^ (row & 7)) << 3)];
            if constexpr (WDT == 0) {
                u16x8 s;
                s[0] = f2bf(pwf[2 * i].x); s[1] = f2bf(pwf[2 * i].y);
                s[2] = f2bf(pwf[2 * i].z); s[3] = f2bf(pwf[2 * i].w);
                s[4] = f2bf(pwf[2 * i + 1].x); s[5] = f2bf(pwf[2 * i + 1].y);
                s[6] = f2bf(pwf[2 * i + 1].z); s[7] = f2bf(pwf[2 * i + 1].w);
                *(u16x8*)dst = s;
            } else {
                *(uint4*)dst = pwb[i];
            }
        }
    };

    issue(0);
    commit(0);
    __syncthreads();

    int buf = 0;
    for (int k0 = 0; k0 < K; k0 += 64) {
        bool nxt = (k0 + 64) < K;
        if (nxt) issue(k0 + 64);
        for (int kk = 0; kk < 64; kk += 32) {
            const int cb = (kk >> 3) + quad;   // 16B chunk index pre-swizzle
            bf16x8 af[4], bfr[JF];
            for (int i = 0; i < 4; ++i) {
                int r = wm + i * 16 + l16;
                af[i] = *(const bf16x8*)&As[buf][r * 64 + ((cb ^ (r & 7)) << 3)];
            }
            for (int j = 0; j < JF; ++j) {
                int rn = wn + j * 16 + l16;
                bfr[j] = *(const bf16x8*)&Bs[buf][rn * 64 + ((cb ^ (rn & 7)) << 3)];
            }
            for (int i = 0; i < 4; ++i)
                for (int j = 0; j < JF; ++j)
                    acc[i][j] = __builtin_amdgcn_mfma_f32_16x16x32_bf16(af[i], bfr[j], acc[i][j], 0, 0, 0);
        }
        if (nxt) {
            commit(buf ^ 1);
            __syncthreads();
            buf ^= 1;
        }
    }

    if constexpr (EPI == 0) {
        for (int i = 0; i < 4; ++i)
            for (int j = 0; j < JF; ++j) {
                int colg = n0 + wn + j * 16 + l16;
                float bv = bias[colg];
                for (int r = 0; r < 4; ++r) {
                    int rowg = wm + i * 16 + quad * 4 + r;
                    C[(size_t)rowg * ldc + colg] = acc[i][j][r] + bv;
                }
            }
    } else {
        for (int i = 0; i < 4; ++i)
            for (int r = 0; r < 4; ++r) {
                int rowg = m0 + wm + i * 16 + quad * 4 + r;
                int b = rowg & 127;
                float partial = 0.0f;
                for (int j = 0; j < JF; ++j) {
                    int colg = n0 + wn + j * 16 + l16;
                    float v = fast_tanh(acc[i][j][r] + hproj[b * 1024 + colg]);
                    partial += v * W2v[colg];
                }
                partial += __shfl_xor(partial, 1, 64);
                partial += __shfl_xor(partial, 2, 64);
                partial += __shfl_xor(partial, 4, 64);
                partial += __shfl_xor(partial, 8, 64);
                if (l16 == 0) atomicAdd(&scores[rowg], partial);
            }
    }
}

// ---------------- softmax + weighted sum over enc ----------------
// grid: 256 blocks = (b, half); each block does 1024 of the 2048 dims, float4/thread
__global__ void __launch_bounds__(256)
attn_combine_k(const float* __restrict__ scores,
               const float* __restrict__ enc,
               unsigned short* __restrict__ xbuf,
               unsigned short* __restrict__ c1) {
    const int b = blockIdx.x >> 1;
    const int half = blockIdx.x & 1;
    const int t = threadIdx.x;
    __shared__ float alpha[128];
    __shared__ float red[256];

    float sc = (t < 128) ? scores[t * 128 + b] : -1e30f;
    red[t] = sc;
    __syncthreads();
    for (int s = 128; s > 0; s >>= 1) {
        if (t < s) red[t] = fmaxf(red[t], red[t + s]);
        __syncthreads();
    }
    float mx = red[0];
    __syncthreads();
    float e = (t < 128) ? __expf(sc - mx) : 0.0f;
    red[t] = e;
    __syncthreads();
    for (int s = 128; s > 0; s >>= 1) {
        if (t < s) red[t] += red[t + s];
        __syncthreads();
    }
    if (t < 128) alpha[t] = e / red[0];
    __syncthreads();

    const int d = half * 1024 + t * 4;
    const float* ep = enc + (size_t)b * 2048 + d;
    float ax = 0.f, ay = 0.f, az = 0.f, aw = 0.f;
#pragma unroll 4
    for (int s = 0; s < 128; ++s) {
        float al = alpha[s];
        float4 v = *(const float4*)(ep + (size_t)s * 128 * 2048);
        ax += al * v.x; ay += al * v.y; az += al * v.z; aw += al * v.w;
    }
    ushort4 s4;
    s4.x = f2bf(ax); s4.y = f2bf(ay); s4.z = f2bf(az); s4.w = f2bf(aw);
    *(ushort4*)&xbuf[b * 2560 + 512 + d] = s4;
    *(ushort4*)&c1[b * 3584 + 1024 + d] = s4;
}

// ---------------- GRU gates ----------------
__global__ void gru_gates_k(const float* __restrict__ gx,
                            const float* __restrict__ gh,
                            const float* __restrict__ dh,
                            float* __restrict__ out_h,
                            unsigned short* __restrict__ c1) {
    int id = blockIdx.x * blockDim.x + threadIdx.x;
    if (id >= 128 * 1024) return;
    int b = id >> 10, h = id & 1023;
    const float* gxb = gx + b * 3072;
    const float* ghb = gh + b * 3072;
    float r = sigmoidf_(gxb[h] + ghb[h]);
    float z = sigmoidf_(gxb[1024 + h] + ghb[1024 + h]);
    float n = fast_tanh(gxb[2048 + h] + r * ghb[2048 + h]);
    float hprev = dh[b * 1024 + h];
    float hnew = (1.0f - z) * n + z * hprev;
    out_h[b * 1024 + h] = hnew;
    c1[b * 3584 + h] = f2bf(hnew);
}

// ---------------- launch ----------------
extern "C" void kernel_launch(void* const* d_in, const int* in_sizes, int n_in,
                              void* d_out, int out_size, void* d_ws, size_t ws_size,
                              hipStream_t stream) {
    const int* tl = (const int*)d_in[0];
    const float* dh = (const float*)d_in[1];
    const float* enc = (const float*)d_in[2];
    const float* emb = (const float*)d_in[3];
    const float* W1 = (const float*)d_in[4];
    const float* b1 = (const float*)d_in[5];
    const float* W2 = (const float*)d_in[6];
    // d_in[7] = b2: softmax shift-invariant -> unused
    const float* Wih = (const float*)d_in[8];
    const float* Whh = (const float*)d_in[9];
    const float* bih = (const float*)d_in[10];
    const float* bhh = (const float*)d_in[11];
    const float* Wout = (const float*)d_in[12];
    const float* bout = (const float*)d_in[13];

    float* out_pred = (float*)d_out;                 // [128, 32000]
    float* out_h = out_pred + (size_t)128 * 32000;   // [128, 1024]

    float* ws = (float*)d_ws;
    float* hproj = ws;                                        // 131072 f
    float* scores = ws + 131072;                              // 16384 f
    unsigned short* xbuf = (unsigned short*)(ws + 147456);    // 327680 bf16
    unsigned short* c1 = (unsigned short*)(ws + 311296);      // 458752 bf16
    float* gx = ws + 540672;                                  // 393216 f
    float* gh = ws + 933888;                                  // 393216 f

    // bf16 weight scratch inside out_pred (dead until the final GEMM)
    unsigned short* w1bf = (unsigned short*)out_pred;          // 1024*3072
    unsigned short* whhbf = w1bf + 1024 * 3072;                // 3072*1024
    unsigned short* wihbf = (unsigned short*)out_pred;         // 3072*2560 (reuse)

    embed_gather_k<<<256, 256, 0, stream>>>(tl, emb, xbuf, c1);

    cvt_bf16_k<<<1536, 256, 0, stream>>>(W1, w1bf, 1024 * 3072 / 8);
    cvt_bf16_k<<<1536, 256, 0, stream>>>(Whh, whhbf, 3072 * 1024 / 8);

    // hproj = dh @ W1[:, 2048:3072]^T + b1   (K=1024, N=1024), W bf16
    gemm_tpl<64, 0, 1, 0><<<16, 256, 0, stream>>>(
        dh, 1024, w1bf + 2048, 3072, b1, hproj, 1024, 1024, nullptr, nullptr, nullptr);

    // gh = dh @ Whh^T + bhh   (K=1024, N=3072), W bf16
    gemm_tpl<64, 0, 1, 0><<<48, 256, 0, stream>>>(
        dh, 1024, whhbf, 1024, bhh, gh, 3072, 1024, nullptr, nullptr, nullptr);

    hipMemsetAsync(scores, 0, 16384 * sizeof(float), stream);

    // scores[m] = sum_n W2[n] * tanh( (enc @ W1e^T)[m,n] + hproj[m&127, n] )
    // grid (8,128): N-fastest so the 8 sharers of each enc slice run concurrently
    dim3 gs(8, 128);
    gemm_tpl<128, 0, 1, 1><<<gs, 256, 0, stream>>>(
        enc, 2048, w1bf, 3072, nullptr, nullptr, 0, 2048, hproj, W2, scores);

    attn_combine_k<<<256, 256, 0, stream>>>(scores, enc, xbuf, c1);

    // Wih -> bf16 (overwrites w1bf/whhbf region; attention GEMMs are done)
    cvt_bf16_k<<<3840, 256, 0, stream>>>(Wih, wihbf, 3072 * 2560 / 8);

    // gx = x @ Wih^T + bih   (A bf16, W bf16, K=2560, N=3072)
    gemm_tpl<64, 1, 1, 0><<<48, 256, 0, stream>>>(
        xbuf, 2560, wihbf, 2560, bih, gx, 3072, 2560, nullptr, nullptr, nullptr);

    gru_gates_k<<<512, 256, 0, stream>>>(gx, gh, dh, out_h, c1);

    // pred = c1 @ Wout^T + bout   (A bf16, W fp32, K=3584, N=32000)
    gemm_tpl<64, 1, 0, 0><<<500, 256, 0, stream>>>(
        c1, 3584, Wout, 3584, bout, out_pred, 32000, 3584, nullptr, nullptr, nullptr);
}